// Round 4
// baseline (201.614 us; speedup 1.0000x reference)
//
#include <hip/hip_runtime.h>
#include <hip/hip_bf16.h>
#include <stdint.h>

typedef __hip_bfloat16 bf16_t;
typedef __attribute__((ext_vector_type(8))) __bf16 bf16x8;
typedef __attribute__((ext_vector_type(4))) float floatx4;

#define BM 128
#define BN 128
#define BK 64

// async 16B global->LDS (wave-uniform base + lane*16; our layouts satisfy this)
__device__ inline void async_load16(const void* g, void* l) {
  __builtin_amdgcn_global_load_lds(
      (const __attribute__((address_space(1))) unsigned int*)g,
      (__attribute__((address_space(3))) unsigned int*)l,
      16, 0, 0);
}

__device__ inline void unpack8_bf16(float* dst, uint4 u) {
  const unsigned w[4] = {u.x, u.y, u.z, u.w};
#pragma unroll
  for (int p = 0; p < 4; ++p) {
    dst[2 * p]     = __uint_as_float(w[p] << 16);
    dst[2 * p + 1] = __uint_as_float(w[p] & 0xffff0000u);
  }
}

__device__ inline unsigned short bf16_bits(float f) {
  bf16_t b = __float2bfloat16(f);
  return *(const unsigned short*)&b;
}

// fp32 -> bf16 for all 5 tensors in one launch + S zero-init.
// blocks: [0,4096) h, then 1024 each Wq/Wk/Wv/Wo, then 2 blocks zero S.
__global__ void cvt_all(const float* __restrict__ h, const float* __restrict__ Wq,
                        const float* __restrict__ Wk, const float* __restrict__ Wv,
                        const float* __restrict__ Wo,
                        bf16_t* __restrict__ hb, bf16_t* __restrict__ Wqb,
                        bf16_t* __restrict__ Wkb, bf16_t* __restrict__ Wvb,
                        bf16_t* __restrict__ Wob, float* __restrict__ S)
{
  const int bid = blockIdx.x;
  if (bid >= 8192) {
    // zero S: 32*64*64 floats = 131072; 512 threads * 64 float4
    float4* s4 = (float4*)S;
    const int base = (bid - 8192) * 256 + threadIdx.x;   // 0..511
#pragma unroll
    for (int i = 0; i < 64; ++i)
      s4[base + i * 512] = (float4){0.f, 0.f, 0.f, 0.f};
    return;
  }
  const float* s; bf16_t* d; int base;
  if (bid < 4096)      { s = h;  d = hb;  base = bid; }
  else if (bid < 5120) { s = Wq; d = Wqb; base = bid - 4096; }
  else if (bid < 6144) { s = Wk; d = Wkb; base = bid - 5120; }
  else if (bid < 7168) { s = Wv; d = Wvb; base = bid - 6144; }
  else                 { s = Wo; d = Wob; base = bid - 7168; }
  const int i = (base * 256 + threadIdx.x) * 4;
  float4 f = *(const float4*)(s + i);
  union { unsigned short u[4]; uint2 v; } p;
  p.u[0] = bf16_bits(f.x); p.u[1] = bf16_bits(f.y);
  p.u[2] = bf16_bits(f.z); p.u[3] = bf16_bits(f.w);
  *(uint2*)(d + i) = p.v;
}

// C[M,N] = A[M,K] * B[N,K]^T ; A,B bf16 row-major; fp32 accum; bf16 out.
// B matrix chosen per 1024-column group of C from {B0,B1,B2} (QKV fusion).
// XOR swizzle: LDS granule slot g of row r holds global granule g^(r&7).
// R2-proven config: (256,2), 4 waves, wave tile 64x64.
__global__ __launch_bounds__(256, 2)
void gemm_nt(const bf16_t* __restrict__ A, int lda,
             const bf16_t* __restrict__ B0, const bf16_t* __restrict__ B1,
             const bf16_t* __restrict__ B2,
             bf16_t* __restrict__ C, int ldc, int Kdim)
{
  __shared__ alignas(16) __bf16 As[BM * BK];
  __shared__ alignas(16) __bf16 Bs[BN * BK];

  const int t = threadIdx.x;
  const int lane = t & 63;
  const int wave = t >> 6;
  const int wm = wave >> 1;   // 0..1
  const int wn = wave & 1;    // 0..1

  const int m0 = blockIdx.x * BM;
  const int nblk = blockIdx.y * BN;
  const int mat = nblk >> 10;
  const bf16_t* __restrict__ B = (mat == 0) ? B0 : ((mat == 1) ? B1 : B2);
  const int n0 = nblk & 1023;

  floatx4 acc[4][4];
#pragma unroll
  for (int i = 0; i < 4; ++i)
#pragma unroll
    for (int j = 0; j < 4; ++j)
      acc[i][j] = (floatx4){0.f, 0.f, 0.f, 0.f};

  const int srow = t >> 3;   // staging row within 32-row chunk
  const int sgs = t & 7;     // LDS granule slot

  for (int k0 = 0; k0 < Kdim; k0 += BK) {
#pragma unroll
    for (int r4 = 0; r4 < 4; ++r4) {
      const int row = r4 * 32 + srow;
      const int gsrc = sgs ^ (row & 7);
      async_load16(A + (size_t)(m0 + row) * lda + k0 + gsrc * 8,
                   &As[row * BK + sgs * 8]);
      async_load16(B + (size_t)(n0 + row) * Kdim + k0 + gsrc * 8,
                   &Bs[row * BK + sgs * 8]);
    }
    __syncthreads();
#pragma unroll
    for (int ks = 0; ks < 2; ++ks) {
      bf16x8 af[4], bfv[4];
#pragma unroll
      for (int i = 0; i < 4; ++i) {
        const int row = wm * 64 + i * 16 + (lane & 15);
        const int g = ks * 4 + (lane >> 4);
        af[i] = *(const bf16x8*)&As[row * BK + (g ^ (row & 7)) * 8];
      }
#pragma unroll
      for (int j = 0; j < 4; ++j) {
        const int row = wn * 64 + j * 16 + (lane & 15);
        const int g = ks * 4 + (lane >> 4);
        bfv[j] = *(const bf16x8*)&Bs[row * BK + (g ^ (row & 7)) * 8];
      }
#pragma unroll
      for (int i = 0; i < 4; ++i)
#pragma unroll
        for (int j = 0; j < 4; ++j)
          acc[i][j] = __builtin_amdgcn_mfma_f32_16x16x32_bf16(
              af[i], bfv[j], acc[i][j], 0, 0, 0);
    }
    __syncthreads();
  }

  const int ccol = lane & 15;
  const int crow = (lane >> 4) * 4;
#pragma unroll
  for (int i = 0; i < 4; ++i) {
#pragma unroll
    for (int j = 0; j < 4; ++j) {
      const int gcol = nblk + wn * 64 + j * 16 + ccol;
      const int growb = m0 + wm * 64 + i * 16 + crow;
#pragma unroll
      for (int r = 0; r < 4; ++r)
        C[(size_t)(growb + r) * ldc + gcol] = __float2bfloat16(acc[i][j][r]);
    }
  }
}

// Split-K NT GEMM, fp32 atomic-add output. blockIdx.z selects K half.
// Same 4-wave 128x128 body as gemm_nt.
__global__ __launch_bounds__(256, 2)
void gemm_nt_splitk(const bf16_t* __restrict__ A, int lda,
                    const bf16_t* __restrict__ B,
                    float* __restrict__ C, int ldc, int Khalf)
{
  __shared__ alignas(16) __bf16 As[BM * BK];
  __shared__ alignas(16) __bf16 Bs[BN * BK];

  const int t = threadIdx.x;
  const int lane = t & 63;
  const int wave = t >> 6;
  const int wm = wave >> 1;
  const int wn = wave & 1;

  const int m0 = blockIdx.x * BM;
  const int n0 = blockIdx.y * BN;
  const int kbase = blockIdx.z * Khalf;

  floatx4 acc[4][4];
#pragma unroll
  for (int i = 0; i < 4; ++i)
#pragma unroll
    for (int j = 0; j < 4; ++j)
      acc[i][j] = (floatx4){0.f, 0.f, 0.f, 0.f};

  const int srow = t >> 3;
  const int sgs = t & 7;

  for (int k0 = kbase; k0 < kbase + Khalf; k0 += BK) {
#pragma unroll
    for (int r4 = 0; r4 < 4; ++r4) {
      const int row = r4 * 32 + srow;
      const int gsrc = sgs ^ (row & 7);
      async_load16(A + (size_t)(m0 + row) * lda + k0 + gsrc * 8,
                   &As[row * BK + sgs * 8]);
      async_load16(B + (size_t)(n0 + row) * 1024 + k0 + gsrc * 8,
                   &Bs[row * BK + sgs * 8]);
    }
    __syncthreads();
#pragma unroll
    for (int ks = 0; ks < 2; ++ks) {
      bf16x8 af[4], bfv[4];
#pragma unroll
      for (int i = 0; i < 4; ++i) {
        const int row = wm * 64 + i * 16 + (lane & 15);
        const int g = ks * 4 + (lane >> 4);
        af[i] = *(const bf16x8*)&As[row * BK + (g ^ (row & 7)) * 8];
      }
#pragma unroll
      for (int j = 0; j < 4; ++j) {
        const int row = wn * 64 + j * 16 + (lane & 15);
        const int g = ks * 4 + (lane >> 4);
        bfv[j] = *(const bf16x8*)&Bs[row * BK + (g ^ (row & 7)) * 8];
      }
#pragma unroll
      for (int i = 0; i < 4; ++i)
#pragma unroll
        for (int j = 0; j < 4; ++j)
          acc[i][j] = __builtin_amdgcn_mfma_f32_16x16x32_bf16(
              af[i], bfv[j], acc[i][j], 0, 0, 0);
    }
    __syncthreads();
  }

  const int ccol = lane & 15;
  const int crow = (lane >> 4) * 4;
#pragma unroll
  for (int i = 0; i < 4; ++i) {
#pragma unroll
    for (int j = 0; j < 4; ++j) {
      const int gcol = n0 + wn * 64 + j * 16 + ccol;
      const int growb = m0 + wm * 64 + i * 16 + crow;
#pragma unroll
      for (int r = 0; r < 4; ++r)
        unsafeAtomicAdd(&C[(size_t)(growb + r) * ldc + gcol], acc[i][j][r]);
    }
  }
}

// S[bh][d][e] += sum_m K[b,m,h,d] * V[b,m,h,e]  (fp32 atomics, m split 16-way)
__global__ __launch_bounds__(256)
void ktv_kernel(const bf16_t* __restrict__ qkv, float* __restrict__ S)
{
  __shared__ float Kf[32][64];
  __shared__ float Vf[32][64];
  const int bh = blockIdx.x;              // b*16 + h
  const int b = bh >> 4, hh = bh & 15;
  const int mc = blockIdx.y;              // 0..15 -> 128 rows each
  const int t = threadIdx.x;
  const int d0 = (t & 15) * 4;
  const int e0 = (t >> 4) * 4;

  const bf16_t* kbase = qkv + (size_t)b * 2048 * 3072 + 1024 + hh * 64;
  const bf16_t* vbase = kbase + 1024;

  float acc[4][4];
#pragma unroll
  for (int i = 0; i < 4; ++i)
#pragma unroll
    for (int j = 0; j < 4; ++j) acc[i][j] = 0.f;

  const int sr = t >> 3;          // 0..31
  const int sc = (t & 7) * 8;     // 0..56

  for (int m0 = mc * 128; m0 < mc * 128 + 128; m0 += 32) {
    uint4 ku = *(const uint4*)(kbase + (size_t)(m0 + sr) * 3072 + sc);
    uint4 vu = *(const uint4*)(vbase + (size_t)(m0 + sr) * 3072 + sc);
    __syncthreads();               // protect previous chunk's reads
    unpack8_bf16(&Kf[sr][sc], ku);
    unpack8_bf16(&Vf[sr][sc], vu);
    __syncthreads();
#pragma unroll
    for (int m = 0; m < 32; ++m) {
      float kv[4], vv[4];
#pragma unroll
      for (int i = 0; i < 4; ++i) kv[i] = Kf[m][d0 + i];
#pragma unroll
      for (int j = 0; j < 4; ++j) vv[j] = Vf[m][e0 + j];
#pragma unroll
      for (int i = 0; i < 4; ++i)
#pragma unroll
        for (int j = 0; j < 4; ++j) acc[i][j] += kv[i] * vv[j];
    }
  }
  float* Sp = S + (size_t)bh * 64 * 64;
#pragma unroll
  for (int i = 0; i < 4; ++i)
#pragma unroll
    for (int j = 0; j < 4; ++j)
      unsafeAtomicAdd(&Sp[(d0 + i) * 64 + e0 + j], acc[i][j]);
}

// O[b,m,h,e] = sum_d Q[b,m,h,d] * S[bh][d][e]; O written into qkv's K-columns.
// Blocks with bh==32 instead zero d_out (needed by the split-K final GEMM).
__global__ __launch_bounds__(256)
void qs_kernel(const bf16_t* __restrict__ qkv, const float* __restrict__ S,
               bf16_t* __restrict__ O, float* __restrict__ out_zero)
{
  const int bh = blockIdx.x;
  const int t = threadIdx.x;
  if (bh == 32) {
    // zero 4096*1024 floats: 16 blocks * 256 thr * 256 float4
    float4* o4 = (float4*)out_zero;
    const int base = blockIdx.y * 256 + t;        // 0..4095
#pragma unroll
    for (int i = 0; i < 256; ++i)
      o4[base + i * 4096] = (float4){0.f, 0.f, 0.f, 0.f};
    return;
  }
  __shared__ float Ss[64][64];
  const int b = bh >> 4, hh = bh & 15;
  const int mt = blockIdx.y;   // 0..15 -> 128 rows each

  const float* Sp = S + (size_t)bh * 4096;
  {
    float* sf = &Ss[0][0];
#pragma unroll
    for (int i = 0; i < 16; ++i) sf[t * 16 + i] = Sp[t * 16 + i];
  }
  __syncthreads();

  const int row = t >> 1;            // 0..127
  const int e0 = (t & 1) * 32;
  const int m = mt * 128 + row;
  const bf16_t* qp = qkv + (size_t)(b * 2048 + m) * 3072 + hh * 64;

  float acc[32];
#pragma unroll
  for (int e = 0; e < 32; ++e) acc[e] = 0.f;

  const uint4* qv = (const uint4*)qp;
#pragma unroll
  for (int c = 0; c < 8; ++c) {
    float qf[8];
    unpack8_bf16(qf, qv[c]);
#pragma unroll
    for (int p = 0; p < 8; ++p) {
      const int d = c * 8 + p;
      const float q = qf[p];
#pragma unroll
      for (int e = 0; e < 32; ++e) acc[e] += q * Ss[d][e0 + e];
    }
  }

  bf16_t* op = O + (size_t)(b * 2048 + m) * 3072 + hh * 64 + e0;
#pragma unroll
  for (int c = 0; c < 4; ++c) {
    uint4 u;
    unsigned* pu = (unsigned*)&u;
#pragma unroll
    for (int p = 0; p < 4; ++p) {
      const int e = c * 8 + p * 2;
      unsigned lo = bf16_bits(acc[e]);
      unsigned hi = bf16_bits(acc[e + 1]);
      pu[p] = lo | (hi << 16);
    }
    ((uint4*)op)[c] = u;
  }
}

extern "C" void kernel_launch(void* const* d_in, const int* in_sizes, int n_in,
                              void* d_out, int out_size, void* d_ws, size_t ws_size,
                              hipStream_t stream)
{
  const float* h  = (const float*)d_in[0];
  const float* Wq = (const float*)d_in[1];
  const float* Wk = (const float*)d_in[2];
  const float* Wv = (const float*)d_in[3];
  // d_in[4] = Wspan: dead code in reference
  const float* Wo = (const float*)d_in[5];
  float* out = (float*)d_out;

  char* ws = (char*)d_ws;
  bf16_t* hb  = (bf16_t*)(ws);                              // [4096,1024] bf16, 8 MB
  bf16_t* Wqb = (bf16_t*)(ws + (8u << 20));                 // 2 MB each
  bf16_t* Wkb = (bf16_t*)(ws + (10u << 20));
  bf16_t* Wvb = (bf16_t*)(ws + (12u << 20));
  bf16_t* Wob = (bf16_t*)(ws + (14u << 20));
  bf16_t* qkv = (bf16_t*)(ws + (16u << 20));                // [4096,3072] bf16, 24 MB
  float*  S   = (float*) (ws + (40u << 20));                // [32,64,64] fp32

  // fp32 -> bf16 conversions + S zero (single launch)
  cvt_all<<<dim3(8194), 256, 0, stream>>>(h, Wq, Wk, Wv, Wo, hb, Wqb, Wkb, Wvb, Wob, S);

  // qkv[:, 0:1024]=Q, [:,1024:2048]=K, [:,2048:3072]=V
  gemm_nt<<<dim3(32, 24), 256, 0, stream>>>(hb, 1024, Wqb, Wkb, Wvb, qkv, 3072, 1024);
  ktv_kernel<<<dim3(32, 16), 256, 0, stream>>>(qkv, S);
  // O overwrites the (now dead) K columns of qkv; bh==32 blocks zero d_out
  qs_kernel<<<dim3(33, 16), 256, 0, stream>>>(qkv, S, qkv + 1024, out);
  // out += O @ Wo^T, split-K=2, fp32 atomic epilogue (2 blocks/CU)
  gemm_nt_splitk<<<dim3(32, 8, 2), 256, 0, stream>>>(qkv + 1024, 3072, Wob, out, 1024, 512);
}

// Round 5
// 189.245 us; speedup vs baseline: 1.0654x; 1.0654x over previous
//
#include <hip/hip_runtime.h>
#include <hip/hip_bf16.h>
#include <stdint.h>

typedef __hip_bfloat16 bf16_t;
typedef __attribute__((ext_vector_type(8))) __bf16 bf16x8;
typedef __attribute__((ext_vector_type(4))) float floatx4;

#define BM 128
#define BN 128
#define BK 64

// async 16B global->LDS (wave-uniform LDS base + lane*16; our layouts satisfy this)
__device__ inline void async_load16(const void* g, void* l) {
  __builtin_amdgcn_global_load_lds(
      (const __attribute__((address_space(1))) unsigned int*)g,
      (__attribute__((address_space(3))) unsigned int*)l,
      16, 0, 0);
}

__device__ inline unsigned short bf16_bits(float f) {
  bf16_t b = __float2bfloat16(f);
  return *(const unsigned short*)&b;
}

// fp32 -> bf16, 4 elements/thread, exact sizes (n % 1024 == 0)
__global__ void cvt_one(const float* __restrict__ src, bf16_t* __restrict__ dst) {
  const int i = (blockIdx.x * 256 + threadIdx.x) * 4;
  float4 f = *(const float4*)(src + i);
  union { unsigned short u[4]; uint2 v; } p;
  p.u[0] = bf16_bits(f.x); p.u[1] = bf16_bits(f.y);
  p.u[2] = bf16_bits(f.z); p.u[3] = bf16_bits(f.w);
  *(uint2*)(dst + i) = p.v;
}

// 4 weight matrices (1024x1024 each) in one launch, selected by blockIdx.y
__global__ void cvt_w4(const float* __restrict__ s0, const float* __restrict__ s1,
                       const float* __restrict__ s2, const float* __restrict__ s3,
                       bf16_t* __restrict__ d0, bf16_t* __restrict__ d1,
                       bf16_t* __restrict__ d2, bf16_t* __restrict__ d3) {
  const float* s; bf16_t* d;
  switch (blockIdx.y) {
    case 0: s = s0; d = d0; break;
    case 1: s = s1; d = d1; break;
    case 2: s = s2; d = d2; break;
    default: s = s3; d = d3; break;
  }
  const int i = (blockIdx.x * 256 + threadIdx.x) * 4;
  float4 f = *(const float4*)(s + i);
  union { unsigned short u[4]; uint2 v; } p;
  p.u[0] = bf16_bits(f.x); p.u[1] = bf16_bits(f.y);
  p.u[2] = bf16_bits(f.z); p.u[3] = bf16_bits(f.w);
  *(uint2*)(d + i) = p.v;
}

// C[M,N] = A[M,K] * B[N,K]^T ; A,B bf16 row-major; fp32 accum; OutT out.
// B matrix chosen per 1024-column group of C from {B0,B1,B2} (QKV fusion).
// XOR swizzle: LDS granule slot g of row r holds global granule g^(r&7).
// R2-proven config: (256,2), 4 waves, wave tile 64x64.
template <typename OutT>
__global__ __launch_bounds__(256, 2)
void gemm_nt(const bf16_t* __restrict__ A, int lda,
             const bf16_t* __restrict__ B0, const bf16_t* __restrict__ B1,
             const bf16_t* __restrict__ B2,
             OutT* __restrict__ C, int ldc, int Kdim)
{
  __shared__ alignas(16) __bf16 As[BM * BK];
  __shared__ alignas(16) __bf16 Bs[BN * BK];

  const int t = threadIdx.x;
  const int lane = t & 63;
  const int wave = t >> 6;
  const int wm = wave >> 1;   // 0..1
  const int wn = wave & 1;    // 0..1

  const int m0 = blockIdx.x * BM;
  const int nblk = blockIdx.y * BN;
  const int mat = nblk >> 10;
  const bf16_t* __restrict__ B = (mat == 0) ? B0 : ((mat == 1) ? B1 : B2);
  const int n0 = nblk & 1023;

  floatx4 acc[4][4];
#pragma unroll
  for (int i = 0; i < 4; ++i)
#pragma unroll
    for (int j = 0; j < 4; ++j)
      acc[i][j] = (floatx4){0.f, 0.f, 0.f, 0.f};

  const int srow = t >> 3;   // staging row within 32-row chunk
  const int sgs = t & 7;     // LDS granule slot

  for (int k0 = 0; k0 < Kdim; k0 += BK) {
#pragma unroll
    for (int r4 = 0; r4 < 4; ++r4) {
      const int row = r4 * 32 + srow;
      const int gsrc = sgs ^ (row & 7);
      async_load16(A + (size_t)(m0 + row) * lda + k0 + gsrc * 8,
                   &As[row * BK + sgs * 8]);
      async_load16(B + (size_t)(n0 + row) * Kdim + k0 + gsrc * 8,
                   &Bs[row * BK + sgs * 8]);
    }
    __syncthreads();
#pragma unroll
    for (int ks = 0; ks < 2; ++ks) {
      bf16x8 af[4], bfv[4];
#pragma unroll
      for (int i = 0; i < 4; ++i) {
        const int row = wm * 64 + i * 16 + (lane & 15);
        const int g = ks * 4 + (lane >> 4);
        af[i] = *(const bf16x8*)&As[row * BK + (g ^ (row & 7)) * 8];
      }
#pragma unroll
      for (int j = 0; j < 4; ++j) {
        const int row = wn * 64 + j * 16 + (lane & 15);
        const int g = ks * 4 + (lane >> 4);
        bfv[j] = *(const bf16x8*)&Bs[row * BK + (g ^ (row & 7)) * 8];
      }
#pragma unroll
      for (int i = 0; i < 4; ++i)
#pragma unroll
        for (int j = 0; j < 4; ++j)
          acc[i][j] = __builtin_amdgcn_mfma_f32_16x16x32_bf16(
              af[i], bfv[j], acc[i][j], 0, 0, 0);
    }
    __syncthreads();
  }

  const int ccol = lane & 15;
  const int crow = (lane >> 4) * 4;
#pragma unroll
  for (int i = 0; i < 4; ++i) {
#pragma unroll
    for (int j = 0; j < 4; ++j) {
      const int gcol = nblk + wn * 64 + j * 16 + ccol;
      const int growb = m0 + wm * 64 + i * 16 + crow;
#pragma unroll
      for (int r = 0; r < 4; ++r) {
        float v = acc[i][j][r];
        if constexpr (__is_same(OutT, bf16_t))
          C[(size_t)(growb + r) * ldc + gcol] = __float2bfloat16(v);
        else
          C[(size_t)(growb + r) * ldc + gcol] = v;
      }
    }
  }
}

// St[bh][e][d] += sum_m V[b,m,h,e] * K[b,m,h,d]
// Direct-from-global (L2-served), no LDS, no barriers. VALU-bound ~5 us.
// grid (32, 16): 128 m-rows per block; fp32 atomic output (S pre-zeroed).
__global__ __launch_bounds__(256, 2)
void ktv_direct(const bf16_t* __restrict__ qkv, float* __restrict__ St)
{
  const int bh = blockIdx.x;              // b*16 + h
  const int b = bh >> 4, hh = bh & 15;
  const int mc = blockIdx.y;              // 0..15 -> 128 rows each
  const int t = threadIdx.x;
  const int d0 = (t & 15) * 4;
  const int e0 = (t >> 4) * 4;

  const bf16_t* kb = qkv + (size_t)b * 2048 * 3072 + 1024 + hh * 64;  // K cols
  const bf16_t* vb = kb + 1024;                                       // V cols

  float acc[4][4];   // [j=e][i=d]
#pragma unroll
  for (int j = 0; j < 4; ++j)
#pragma unroll
    for (int i = 0; i < 4; ++i) acc[j][i] = 0.f;

  const int mend = mc * 128 + 128;
#pragma unroll 4
  for (int m = mc * 128; m < mend; ++m) {
    const uint2 ku = *(const uint2*)(kb + (size_t)m * 3072 + d0);
    const uint2 vu = *(const uint2*)(vb + (size_t)m * 3072 + e0);
    float kf[4], vf[4];
    kf[0] = __uint_as_float(ku.x << 16); kf[1] = __uint_as_float(ku.x & 0xffff0000u);
    kf[2] = __uint_as_float(ku.y << 16); kf[3] = __uint_as_float(ku.y & 0xffff0000u);
    vf[0] = __uint_as_float(vu.x << 16); vf[1] = __uint_as_float(vu.x & 0xffff0000u);
    vf[2] = __uint_as_float(vu.y << 16); vf[3] = __uint_as_float(vu.y & 0xffff0000u);
#pragma unroll
    for (int j = 0; j < 4; ++j)
#pragma unroll
      for (int i = 0; i < 4; ++i) acc[j][i] += vf[j] * kf[i];
  }
  float* Sp = St + (size_t)bh * 4096;
#pragma unroll
  for (int j = 0; j < 4; ++j)
#pragma unroll
    for (int i = 0; i < 4; ++i)
      unsafeAtomicAdd(&Sp[(e0 + j) * 64 + (d0 + i)], acc[j][i]);
}

// O[m][h*64+e] = sum_d Q[m][h*64+d] * S[d][e], via MFMA.
// A-frag: Q tile (128 x 64) staged by global_load_lds w/ XOR swizzle.
// B-frag: St[e][d] (d-contiguous), fp32 -> bf16 converted into LDS.
// O written into qkv's (dead) K columns. grid (32 bh, 16 mt).
__global__ __launch_bounds__(256, 2)
void qs_mfma(const bf16_t* __restrict__ qkv, const float* __restrict__ St,
             bf16_t* __restrict__ O)
{
  __shared__ alignas(16) __bf16 Qs[128 * 64];
  __shared__ alignas(16) __bf16 Sb[64 * 64];

  const int t = threadIdx.x;
  const int lane = t & 63;
  const int wave = t >> 6;          // 0..3 -> 32-row m strip
  const int bh = blockIdx.x;
  const int b = bh >> 4, hh = bh & 15;
  const int mt = blockIdx.y;        // 0..15 -> 128 m rows

  // stage Q tile: global rows mt*128 .. +128, cols hh*64 .. +64
  const bf16_t* qbase = qkv + (size_t)(b * 2048 + mt * 128) * 3072 + hh * 64;
  const int srow = t >> 3;          // 0..31
  const int sgs = t & 7;            // granule slot
#pragma unroll
  for (int r4 = 0; r4 < 4; ++r4) {
    const int row = r4 * 32 + srow;
    const int gsrc = sgs ^ (row & 7);
    async_load16(qbase + (size_t)row * 3072 + gsrc * 8, &Qs[row * 64 + sgs * 8]);
  }
  // stage St (fp32 -> bf16), same XOR-swizzled granule layout
  {
    const int r = t >> 2;           // 0..63 (e row)
    const int g0 = (t & 3) * 2;     // two granule slots per thread
    const float* sp = St + (size_t)bh * 4096 + r * 64;
#pragma unroll
    for (int gg = 0; gg < 2; ++gg) {
      const int g = g0 + gg;                 // LDS granule slot
      const int gs = g ^ (r & 7);            // source global granule
      const float4 f0 = *(const float4*)(sp + gs * 8);
      const float4 f1 = *(const float4*)(sp + gs * 8 + 4);
      union { unsigned short u[8]; uint4 v; } pk;
      pk.u[0] = bf16_bits(f0.x); pk.u[1] = bf16_bits(f0.y);
      pk.u[2] = bf16_bits(f0.z); pk.u[3] = bf16_bits(f0.w);
      pk.u[4] = bf16_bits(f1.x); pk.u[5] = bf16_bits(f1.y);
      pk.u[6] = bf16_bits(f1.z); pk.u[7] = bf16_bits(f1.w);
      *(uint4*)&Sb[r * 64 + g * 8] = pk.v;
    }
  }
  __syncthreads();

  floatx4 acc[2][4];
#pragma unroll
  for (int i = 0; i < 2; ++i)
#pragma unroll
    for (int j = 0; j < 4; ++j)
      acc[i][j] = (floatx4){0.f, 0.f, 0.f, 0.f};

#pragma unroll
  for (int ks = 0; ks < 2; ++ks) {
    bf16x8 af[2], bfv[4];
#pragma unroll
    for (int i = 0; i < 2; ++i) {
      const int row = wave * 32 + i * 16 + (lane & 15);
      const int g = ks * 4 + (lane >> 4);
      af[i] = *(const bf16x8*)&Qs[row * 64 + (g ^ (row & 7)) * 8];
    }
#pragma unroll
    for (int j = 0; j < 4; ++j) {
      const int row = j * 16 + (lane & 15);       // e
      const int g = ks * 4 + (lane >> 4);
      bfv[j] = *(const bf16x8*)&Sb[row * 64 + (g ^ (row & 7)) * 8];
    }
#pragma unroll
    for (int i = 0; i < 2; ++i)
#pragma unroll
      for (int j = 0; j < 4; ++j)
        acc[i][j] = __builtin_amdgcn_mfma_f32_16x16x32_bf16(
            af[i], bfv[j], acc[i][j], 0, 0, 0);
  }

  // epilogue: C[m][e] -> O rows b*2048+mt*128+m, cols hh*64+e
  const int ccol = lane & 15;
  const int crow = (lane >> 4) * 4;
#pragma unroll
  for (int i = 0; i < 2; ++i) {
#pragma unroll
    for (int j = 0; j < 4; ++j) {
      const int e = hh * 64 + j * 16 + ccol;
      const int mrow = mt * 128 + wave * 32 + i * 16 + crow;
#pragma unroll
      for (int r = 0; r < 4; ++r)
        O[(size_t)(b * 2048 + mrow + r) * 3072 + e] = __float2bfloat16(acc[i][j][r]);
    }
  }
}

extern "C" void kernel_launch(void* const* d_in, const int* in_sizes, int n_in,
                              void* d_out, int out_size, void* d_ws, size_t ws_size,
                              hipStream_t stream)
{
  const float* h  = (const float*)d_in[0];
  const float* Wq = (const float*)d_in[1];
  const float* Wk = (const float*)d_in[2];
  const float* Wv = (const float*)d_in[3];
  // d_in[4] = Wspan: dead code in reference
  const float* Wo = (const float*)d_in[5];
  float* out = (float*)d_out;

  char* ws = (char*)d_ws;
  bf16_t* hb  = (bf16_t*)(ws);                              // [4096,1024] bf16, 8 MB
  bf16_t* Wqb = (bf16_t*)(ws + (8u << 20));                 // 2 MB each
  bf16_t* Wkb = (bf16_t*)(ws + (10u << 20));
  bf16_t* Wvb = (bf16_t*)(ws + (12u << 20));
  bf16_t* Wob = (bf16_t*)(ws + (14u << 20));
  bf16_t* qkv = (bf16_t*)(ws + (16u << 20));                // [4096,3072] bf16, 24 MB
  float*  St  = (float*) (ws + (40u << 20));                // [32,64,64] fp32 (S^T, e-major)

  hipMemsetAsync(St, 0, 32 * 64 * 64 * sizeof(float), stream);

  // fp32 -> bf16 conversions
  cvt_one<<<dim3(4096), 256, 0, stream>>>(h, hb);
  cvt_w4<<<dim3(1024, 4), 256, 0, stream>>>(Wq, Wk, Wv, Wo, Wqb, Wkb, Wvb, Wob);

  // qkv[:, 0:1024]=Q, [:,1024:2048]=K, [:,2048:3072]=V
  gemm_nt<bf16_t><<<dim3(32, 24), 256, 0, stream>>>(hb, 1024, Wqb, Wkb, Wvb, qkv, 3072, 1024);
  // St[bh][e][d] = sum_m V*K  (direct from L2, atomic fp32)
  ktv_direct<<<dim3(32, 16), 256, 0, stream>>>(qkv, St);
  // O = Q @ S per head (MFMA); O overwrites the (now dead) K columns of qkv
  qs_mfma<<<dim3(32, 16), 256, 0, stream>>>(qkv, St, qkv + 1024);
  // out = O @ Wo^T, fp32 epilogue
  gemm_nt<float><<<dim3(32, 8), 256, 0, stream>>>(qkv + 1024, 3072, Wob, Wob, Wob, out, 1024, 1024);
}

// Round 6
// 148.377 us; speedup vs baseline: 1.3588x; 1.2754x over previous
//
#include <hip/hip_runtime.h>
#include <hip/hip_bf16.h>
#include <stdint.h>

typedef __hip_bfloat16 bf16_t;
typedef __attribute__((ext_vector_type(8))) __bf16 bf16x8;
typedef __attribute__((ext_vector_type(4))) float floatx4;

#define BM 128
#define BN 128
#define BK 64

// async 16B global->LDS (wave-uniform LDS base + lane*16; our layouts satisfy this)
__device__ inline void async_load16(const void* g, void* l) {
  __builtin_amdgcn_global_load_lds(
      (const __attribute__((address_space(1))) unsigned int*)g,
      (__attribute__((address_space(3))) unsigned int*)l,
      16, 0, 0);
}

__device__ inline unsigned short bf16_bits(float f) {
  bf16_t b = __float2bfloat16(f);
  return *(const unsigned short*)&b;
}

// fp32 -> bf16, 4 elements/thread, exact sizes (n % 1024 == 0)
__global__ void cvt_one(const float* __restrict__ src, bf16_t* __restrict__ dst) {
  const int i = (blockIdx.x * 256 + threadIdx.x) * 4;
  float4 f = *(const float4*)(src + i);
  union { unsigned short u[4]; uint2 v; } p;
  p.u[0] = bf16_bits(f.x); p.u[1] = bf16_bits(f.y);
  p.u[2] = bf16_bits(f.z); p.u[3] = bf16_bits(f.w);
  *(uint2*)(dst + i) = p.v;
}

// 4 weight matrices (1024x1024 each) in one launch, selected by blockIdx.y
__global__ void cvt_w4(const float* __restrict__ s0, const float* __restrict__ s1,
                       const float* __restrict__ s2, const float* __restrict__ s3,
                       bf16_t* __restrict__ d0, bf16_t* __restrict__ d1,
                       bf16_t* __restrict__ d2, bf16_t* __restrict__ d3) {
  const float* s; bf16_t* d;
  switch (blockIdx.y) {
    case 0: s = s0; d = d0; break;
    case 1: s = s1; d = d1; break;
    case 2: s = s2; d = d2; break;
    default: s = s3; d = d3; break;
  }
  const int i = (blockIdx.x * 256 + threadIdx.x) * 4;
  float4 f = *(const float4*)(s + i);
  union { unsigned short u[4]; uint2 v; } p;
  p.u[0] = bf16_bits(f.x); p.u[1] = bf16_bits(f.y);
  p.u[2] = bf16_bits(f.z); p.u[3] = bf16_bits(f.w);
  *(uint2*)(d + i) = p.v;
}

// C[M,N] = A[M,K] * B[N,K]^T ; A,B bf16 row-major; fp32 accum.
// TKV mode (QKV GEMM): mat0 -> C=Qbuf (ldc), mat1/mat2 -> Kt/Vt written
// TRANSPOSED as [bh][64 d|e][2048 m] (each lane stores 4 contiguous m as uint2).
// XOR swizzle: LDS granule slot g of row r holds global granule g^(r&7).
template <typename OutT, bool TKV>
__global__ __launch_bounds__(256, 2)
void gemm_nt(const bf16_t* __restrict__ A, int lda,
             const bf16_t* __restrict__ B0, const bf16_t* __restrict__ B1,
             const bf16_t* __restrict__ B2,
             OutT* __restrict__ C, int ldc, int Kdim,
             bf16_t* __restrict__ Kt, bf16_t* __restrict__ Vt)
{
  __shared__ alignas(16) __bf16 As[BM * BK];
  __shared__ alignas(16) __bf16 Bs[BN * BK];

  const int t = threadIdx.x;
  const int lane = t & 63;
  const int wave = t >> 6;
  const int wm = wave >> 1;   // 0..1
  const int wn = wave & 1;    // 0..1

  const int m0 = blockIdx.x * BM;
  const int nblk = blockIdx.y * BN;
  const int mat = nblk >> 10;
  const bf16_t* __restrict__ B = (mat == 0) ? B0 : ((mat == 1) ? B1 : B2);
  const int n0 = nblk & 1023;

  floatx4 acc[4][4];
#pragma unroll
  for (int i = 0; i < 4; ++i)
#pragma unroll
    for (int j = 0; j < 4; ++j)
      acc[i][j] = (floatx4){0.f, 0.f, 0.f, 0.f};

  const int srow = t >> 3;   // staging row within 32-row chunk
  const int sgs = t & 7;     // LDS granule slot

  for (int k0 = 0; k0 < Kdim; k0 += BK) {
#pragma unroll
    for (int r4 = 0; r4 < 4; ++r4) {
      const int row = r4 * 32 + srow;
      const int gsrc = sgs ^ (row & 7);
      async_load16(A + (size_t)(m0 + row) * lda + k0 + gsrc * 8,
                   &As[row * BK + sgs * 8]);
      async_load16(B + (size_t)(n0 + row) * Kdim + k0 + gsrc * 8,
                   &Bs[row * BK + sgs * 8]);
    }
    __syncthreads();
#pragma unroll
    for (int ks = 0; ks < 2; ++ks) {
      bf16x8 af[4], bfv[4];
#pragma unroll
      for (int i = 0; i < 4; ++i) {
        const int row = wm * 64 + i * 16 + (lane & 15);
        const int g = ks * 4 + (lane >> 4);
        af[i] = *(const bf16x8*)&As[row * BK + (g ^ (row & 7)) * 8];
      }
#pragma unroll
      for (int j = 0; j < 4; ++j) {
        const int row = wn * 64 + j * 16 + (lane & 15);
        const int g = ks * 4 + (lane >> 4);
        bfv[j] = *(const bf16x8*)&Bs[row * BK + (g ^ (row & 7)) * 8];
      }
#pragma unroll
      for (int i = 0; i < 4; ++i)
#pragma unroll
        for (int j = 0; j < 4; ++j)
          acc[i][j] = __builtin_amdgcn_mfma_f32_16x16x32_bf16(
              af[i], bfv[j], acc[i][j], 0, 0, 0);
    }
    __syncthreads();
  }

  const int ccol = lane & 15;
  const int crow = (lane >> 4) * 4;

  if constexpr (TKV) {
    if (mat != 0) {
      bf16_t* __restrict__ T = (mat == 1) ? Kt : Vt;
#pragma unroll
      for (int i = 0; i < 4; ++i) {
#pragma unroll
        for (int j = 0; j < 4; ++j) {
          const int lc = n0 + wn * 64 + j * 16 + ccol;   // 0..1023
          const int hidx = lc >> 6, d = lc & 63;
          const int grow = m0 + wm * 64 + i * 16 + crow; // global row (incl b)
          const int bidx = grow >> 11, mloc = grow & 2047;
          union { unsigned short u[4]; uint2 v; } p;
#pragma unroll
          for (int r = 0; r < 4; ++r) p.u[r] = bf16_bits(acc[i][j][r]);
          *(uint2*)(T + (((size_t)bidx * 16 + hidx) * 64 + d) * 2048 + mloc) = p.v;
        }
      }
      return;
    }
  }

#pragma unroll
  for (int i = 0; i < 4; ++i) {
#pragma unroll
    for (int j = 0; j < 4; ++j) {
      const int gcol = n0 + wn * 64 + j * 16 + ccol;
      const int growb = m0 + wm * 64 + i * 16 + crow;
#pragma unroll
      for (int r = 0; r < 4; ++r) {
        float v = acc[i][j][r];
        if constexpr (__is_same(OutT, bf16_t))
          C[(size_t)(growb + r) * ldc + gcol] = __float2bfloat16(v);
        else
          C[(size_t)(growb + r) * ldc + gcol] = v;
      }
    }
  }
}

// St[bh][e][d] += sum_m Vt[bh][e][m] * Kt[bh][d][m]  -- pure NT MFMA GEMM.
// grid (32 bh, 8 ksplit); 64x64 tile, BK=64, 4 k-steps; fp32 atomic epilogue.
__global__ __launch_bounds__(256, 2)
void ktv_gemm(const bf16_t* __restrict__ Kt, const bf16_t* __restrict__ Vt,
              float* __restrict__ St)
{
  __shared__ alignas(16) __bf16 As[64 * 64];   // Vt tile (e rows)
  __shared__ alignas(16) __bf16 Bs[64 * 64];   // Kt tile (d rows)

  const int t = threadIdx.x;
  const int lane = t & 63;
  const int wave = t >> 6;            // e-strip = wave*16
  const int bh = blockIdx.x;
  const int kc = blockIdx.y;          // k-range kc*256 .. +256

  const bf16_t* A = Vt + (size_t)bh * 64 * 2048;
  const bf16_t* B = Kt + (size_t)bh * 64 * 2048;

  floatx4 acc[4];
#pragma unroll
  for (int j = 0; j < 4; ++j) acc[j] = (floatx4){0.f, 0.f, 0.f, 0.f};

  const int srow = t >> 3;   // 0..31
  const int sgs = t & 7;

  for (int k0 = kc * 256; k0 < kc * 256 + 256; k0 += 64) {
#pragma unroll
    for (int r2 = 0; r2 < 2; ++r2) {
      const int row = r2 * 32 + srow;
      const int gsrc = sgs ^ (row & 7);
      async_load16(A + (size_t)row * 2048 + k0 + gsrc * 8, &As[row * 64 + sgs * 8]);
      async_load16(B + (size_t)row * 2048 + k0 + gsrc * 8, &Bs[row * 64 + sgs * 8]);
    }
    __syncthreads();
#pragma unroll
    for (int ks = 0; ks < 2; ++ks) {
      bf16x8 af, bfv[4];
      {
        const int row = wave * 16 + (lane & 15);
        const int g = ks * 4 + (lane >> 4);
        af = *(const bf16x8*)&As[row * 64 + (g ^ (row & 7)) * 8];
      }
#pragma unroll
      for (int j = 0; j < 4; ++j) {
        const int row = j * 16 + (lane & 15);
        const int g = ks * 4 + (lane >> 4);
        bfv[j] = *(const bf16x8*)&Bs[row * 64 + (g ^ (row & 7)) * 8];
      }
#pragma unroll
      for (int j = 0; j < 4; ++j)
        acc[j] = __builtin_amdgcn_mfma_f32_16x16x32_bf16(af, bfv[j], acc[j], 0, 0, 0);
    }
    __syncthreads();
  }

  // C[e][d]: e = wave*16 + crow + r, d = j*16 + ccol
  const int ccol = lane & 15;
  const int crow = (lane >> 4) * 4;
  float* Sp = St + (size_t)bh * 4096;
#pragma unroll
  for (int j = 0; j < 4; ++j)
#pragma unroll
    for (int r = 0; r < 4; ++r)
      unsafeAtomicAdd(&Sp[(wave * 16 + crow + r) * 64 + j * 16 + ccol], acc[j][r]);
}

// O[m][h*64+e] = sum_d Q[m][h*64+d] * St[e][d], via MFMA.
// Q from Qbuf [4096x1024]; O to Obuf [4096x1024]. grid (32 bh, 16 mt).
__global__ __launch_bounds__(256, 2)
void qs_mfma(const bf16_t* __restrict__ Qbuf, const float* __restrict__ St,
             bf16_t* __restrict__ O)
{
  __shared__ alignas(16) __bf16 Qs[128 * 64];
  __shared__ alignas(16) __bf16 Sb[64 * 64];

  const int t = threadIdx.x;
  const int lane = t & 63;
  const int wave = t >> 6;          // 0..3 -> 32-row m strip
  const int bh = blockIdx.x;
  const int b = bh >> 4, hh = bh & 15;
  const int mt = blockIdx.y;        // 0..15 -> 128 m rows

  // stage Q tile: rows mt*128 .. +128, cols hh*64 .. +64
  const bf16_t* qbase = Qbuf + (size_t)(b * 2048 + mt * 128) * 1024 + hh * 64;
  const int srow = t >> 3;          // 0..31
  const int sgs = t & 7;            // granule slot
#pragma unroll
  for (int r4 = 0; r4 < 4; ++r4) {
    const int row = r4 * 32 + srow;
    const int gsrc = sgs ^ (row & 7);
    async_load16(qbase + (size_t)row * 1024 + gsrc * 8, &Qs[row * 64 + sgs * 8]);
  }
  // stage St (fp32 -> bf16), same XOR-swizzled granule layout
  {
    const int r = t >> 2;           // 0..63 (e row)
    const int g0 = (t & 3) * 2;     // two granule slots per thread
    const float* sp = St + (size_t)bh * 4096 + r * 64;
#pragma unroll
    for (int gg = 0; gg < 2; ++gg) {
      const int g = g0 + gg;                 // LDS granule slot
      const int gs = g ^ (r & 7);            // source global granule
      const float4 f0 = *(const float4*)(sp + gs * 8);
      const float4 f1 = *(const float4*)(sp + gs * 8 + 4);
      union { unsigned short u[8]; uint4 v; } pk;
      pk.u[0] = bf16_bits(f0.x); pk.u[1] = bf16_bits(f0.y);
      pk.u[2] = bf16_bits(f0.z); pk.u[3] = bf16_bits(f0.w);
      pk.u[4] = bf16_bits(f1.x); pk.u[5] = bf16_bits(f1.y);
      pk.u[6] = bf16_bits(f1.z); pk.u[7] = bf16_bits(f1.w);
      *(uint4*)&Sb[r * 64 + g * 8] = pk.v;
    }
  }
  __syncthreads();

  floatx4 acc[2][4];
#pragma unroll
  for (int i = 0; i < 2; ++i)
#pragma unroll
    for (int j = 0; j < 4; ++j)
      acc[i][j] = (floatx4){0.f, 0.f, 0.f, 0.f};

#pragma unroll
  for (int ks = 0; ks < 2; ++ks) {
    bf16x8 af[2], bfv[4];
#pragma unroll
    for (int i = 0; i < 2; ++i) {
      const int row = wave * 32 + i * 16 + (lane & 15);
      const int g = ks * 4 + (lane >> 4);
      af[i] = *(const bf16x8*)&Qs[row * 64 + (g ^ (row & 7)) * 8];
    }
#pragma unroll
    for (int j = 0; j < 4; ++j) {
      const int row = j * 16 + (lane & 15);       // e
      const int g = ks * 4 + (lane >> 4);
      bfv[j] = *(const bf16x8*)&Sb[row * 64 + (g ^ (row & 7)) * 8];
    }
#pragma unroll
    for (int i = 0; i < 2; ++i)
#pragma unroll
      for (int j = 0; j < 4; ++j)
        acc[i][j] = __builtin_amdgcn_mfma_f32_16x16x32_bf16(
            af[i], bfv[j], acc[i][j], 0, 0, 0);
  }

  // epilogue: C[m][e] -> Obuf rows b*2048+mt*128+m, cols hh*64+e
  const int ccol = lane & 15;
  const int crow = (lane >> 4) * 4;
#pragma unroll
  for (int i = 0; i < 2; ++i) {
#pragma unroll
    for (int j = 0; j < 4; ++j) {
      const int col = hh * 64 + j * 16 + ccol;
      const int mrow = mt * 128 + wave * 32 + i * 16 + crow;
#pragma unroll
      for (int r = 0; r < 4; ++r)
        O[(size_t)(b * 2048 + mrow + r) * 1024 + col] = __float2bfloat16(acc[i][j][r]);
    }
  }
}

extern "C" void kernel_launch(void* const* d_in, const int* in_sizes, int n_in,
                              void* d_out, int out_size, void* d_ws, size_t ws_size,
                              hipStream_t stream)
{
  const float* h  = (const float*)d_in[0];
  const float* Wq = (const float*)d_in[1];
  const float* Wk = (const float*)d_in[2];
  const float* Wv = (const float*)d_in[3];
  // d_in[4] = Wspan: dead code in reference
  const float* Wo = (const float*)d_in[5];
  float* out = (float*)d_out;

  char* ws = (char*)d_ws;
  bf16_t* hb   = (bf16_t*)(ws);                 // [4096,1024] bf16, 8 MB (dead after QKV GEMM)
  bf16_t* Obuf = (bf16_t*)(ws);                 // reuses hb's slot
  bf16_t* Wqb  = (bf16_t*)(ws + (8u << 20));    // 2 MB each
  bf16_t* Wkb  = (bf16_t*)(ws + (10u << 20));
  bf16_t* Wvb  = (bf16_t*)(ws + (12u << 20));
  bf16_t* Wob  = (bf16_t*)(ws + (14u << 20));
  bf16_t* Qbuf = (bf16_t*)(ws + (16u << 20));   // [4096,1024] bf16, 8 MB
  bf16_t* Kt   = (bf16_t*)(ws + (24u << 20));   // [32][64][2048] bf16, 8 MB
  bf16_t* Vt   = (bf16_t*)(ws + (32u << 20));   // [32][64][2048] bf16, 8 MB
  float*  St   = (float*) (ws + (40u << 20));   // [32][64][64] fp32 (S^T, e-major)

  hipMemsetAsync(St, 0, 32 * 64 * 64 * sizeof(float), stream);

  // fp32 -> bf16 conversions
  cvt_one<<<dim3(4096), 256, 0, stream>>>(h, hb);
  cvt_w4<<<dim3(1024, 4), 256, 0, stream>>>(Wq, Wk, Wv, Wo, Wqb, Wkb, Wvb, Wob);

  // Q -> Qbuf (row-major); K,V -> Kt,Vt (transposed, m-contiguous)
  gemm_nt<bf16_t, true><<<dim3(32, 24), 256, 0, stream>>>(
      hb, 1024, Wqb, Wkb, Wvb, Qbuf, 1024, 1024, Kt, Vt);
  // St[bh][e][d] = sum_m V*K  (MFMA NT GEMM, split-K=8, atomic fp32)
  ktv_gemm<<<dim3(32, 8), 256, 0, stream>>>(Kt, Vt, St);
  // O = Q @ S per head (MFMA) -> Obuf
  qs_mfma<<<dim3(32, 16), 256, 0, stream>>>(Qbuf, St, Obuf);
  // out = O @ Wo^T, fp32 epilogue
  gemm_nt<float, false><<<dim3(32, 8), 256, 0, stream>>>(
      Obuf, 1024, Wob, Wob, Wob, out, 1024, 1024, nullptr, nullptr);
}